// Round 1
// baseline (1973.869 us; speedup 1.0000x reference)
//
#include <hip/hip_runtime.h>
#include <hip/hip_bf16.h>
#include <math.h>

#define DEMB 64

// ---------------- graph preprocessing ----------------

__global__ void init_kernel(float* __restrict__ deg, int* __restrict__ cnt,
                            int* __restrict__ fill, int N) {
    int i = blockIdx.x * blockDim.x + threadIdx.x;
    if (i >= N) return;
    deg[i] = 1.0f;   // self-loop weight
    cnt[i] = 0;
    fill[i] = 0;
}

__global__ void deg_hist_kernel(const int* __restrict__ ei, const float* __restrict__ ew,
                                float* __restrict__ deg, int* __restrict__ cnt, int E) {
    int e = blockIdx.x * blockDim.x + threadIdx.x;
    if (e >= E) return;
    int c = ei[E + e];           // col (target)
    atomicAdd(&deg[c], ew[e]);
    atomicAdd(&cnt[c], 1);
}

__global__ void dis_kernel(float* __restrict__ deg, int N) {
    int i = blockIdx.x * blockDim.x + threadIdx.x;
    if (i >= N) return;
    deg[i] = rsqrtf(deg[i]);     // deg >= 1 always (self loop)
}

// single-block exclusive scan of cnt -> rowptr (rowptr[N] = E)
__global__ void scan_kernel(const int* __restrict__ cnt, int* __restrict__ rowptr, int N) {
    __shared__ int part[1024];
    int t = threadIdx.x;
    int chunk = (N + 1023) >> 10;
    int lo = t * chunk;
    int hi = lo + chunk; if (hi > N) hi = N;
    int s = 0;
    for (int i = lo; i < hi; i++) s += cnt[i];
    part[t] = s;
    __syncthreads();
    for (int off = 1; off < 1024; off <<= 1) {
        int v = (t >= off) ? part[t - off] : 0;
        __syncthreads();
        part[t] += v;
        __syncthreads();
    }
    int run = part[t] - s;       // exclusive prefix
    for (int i = lo; i < hi; i++) { rowptr[i] = run; run += cnt[i]; }
    if (lo < N && hi == N) rowptr[N] = run;
}

__global__ void csr_fill_kernel(const int* __restrict__ ei, const float* __restrict__ ew,
                                const float* __restrict__ dis, const int* __restrict__ rowptr,
                                int* __restrict__ fill, int* __restrict__ csr_src,
                                float* __restrict__ csr_w, int E) {
    int e = blockIdx.x * blockDim.x + threadIdx.x;
    if (e >= E) return;
    int r = ei[e];
    int c = ei[E + e];
    int pos = rowptr[c] + atomicAdd(&fill[c], 1);
    csr_src[pos] = r;
    csr_w[pos] = dis[r] * ew[e] * dis[c];
}

// ---------------- dense layers (thread-per-node) ----------------

__global__ void encoder_kernel(const float* __restrict__ x,
                               const float* __restrict__ w1, const float* __restrict__ b1,
                               const float* __restrict__ w2, const float* __restrict__ b2,
                               float* __restrict__ hout, int N) {
    int n = blockIdx.x * blockDim.x + threadIdx.x;
    if (n >= N) return;
    float x0 = x[2 * n], x1 = x[2 * n + 1];
    float t[DEMB];
    #pragma unroll
    for (int k = 0; k < DEMB; k++)
        t[k] = fmaxf(0.0f, fmaf(x0, w1[k], fmaf(x1, w1[DEMB + k], b1[k])));
    float* orow = hout + (size_t)n * DEMB;
    for (int jc = 0; jc < 4; jc++) {
        float acc[16];
        #pragma unroll
        for (int jj = 0; jj < 16; jj++) acc[jj] = b2[jc * 16 + jj];
        #pragma unroll
        for (int k = 0; k < DEMB; k++) {
            float hk = t[k];
            #pragma unroll
            for (int jj = 0; jj < 16; jj++)
                acc[jj] = fmaf(hk, w2[k * DEMB + jc * 16 + jj], acc[jj]);
        }
        #pragma unroll
        for (int q = 0; q < 4; q++) {
            float4 s = make_float4(acc[q*4], acc[q*4+1], acc[q*4+2], acc[q*4+3]);
            *(float4*)(orow + jc * 16 + q * 4) = s;   // no ReLU on encoder output
        }
    }
}

__global__ void transform_kernel(const float* __restrict__ h, const float* __restrict__ W,
                                 float* __restrict__ hw, int N) {
    int n = blockIdx.x * blockDim.x + threadIdx.x;
    if (n >= N) return;
    float hr[DEMB];
    const float* row = h + (size_t)n * DEMB;
    #pragma unroll
    for (int q = 0; q < 16; q++) {
        float4 v = *(const float4*)(row + q * 4);
        hr[q*4] = v.x; hr[q*4+1] = v.y; hr[q*4+2] = v.z; hr[q*4+3] = v.w;
    }
    float* orow = hw + (size_t)n * DEMB;
    for (int jc = 0; jc < 4; jc++) {
        float acc[16];
        #pragma unroll
        for (int jj = 0; jj < 16; jj++) acc[jj] = 0.0f;
        #pragma unroll
        for (int k = 0; k < DEMB; k++) {
            float hk = hr[k];
            #pragma unroll
            for (int jj = 0; jj < 16; jj++)
                acc[jj] = fmaf(hk, W[k * DEMB + jc * 16 + jj], acc[jj]);
        }
        #pragma unroll
        for (int q = 0; q < 4; q++) {
            float4 s = make_float4(acc[q*4], acc[q*4+1], acc[q*4+2], acc[q*4+3]);
            *(float4*)(orow + jc * 16 + q * 4) = s;
        }
    }
}

// ---------------- aggregation: wave-per-node, lane = feature ----------------

__global__ void aggregate_kernel(const float* __restrict__ hw, const int* __restrict__ rowptr,
                                 const int* __restrict__ csr_src, const float* __restrict__ csr_w,
                                 const float* __restrict__ dis, const float* __restrict__ bias,
                                 float* __restrict__ hout, int N) {
    int wid = (blockIdx.x * blockDim.x + threadIdx.x) >> 6;
    int lane = threadIdx.x & 63;
    if (wid >= N) return;
    float d = dis[wid];
    float acc = d * d * hw[(size_t)wid * DEMB + lane];   // self loop: norm = dis^2
    int s = rowptr[wid], e = rowptr[wid + 1];
    for (int i = s; i < e; i++) {
        int src = csr_src[i];
        float w = csr_w[i];
        acc = fmaf(w, hw[(size_t)src * DEMB + lane], acc);
    }
    hout[(size_t)wid * DEMB + lane] = fmaxf(acc + bias[lane], 0.0f);
}

// ---------------- decoder + softmax + residual ----------------

__global__ void decoder_kernel(const float* __restrict__ h, const float* __restrict__ x,
                               const float* __restrict__ dw1, const float* __restrict__ db1,
                               const float* __restrict__ dw2, const float* __restrict__ db2,
                               float* __restrict__ out, int N) {
    int n = blockIdx.x * blockDim.x + threadIdx.x;
    if (n >= N) return;
    float hr[DEMB];
    const float* row = h + (size_t)n * DEMB;
    #pragma unroll
    for (int q = 0; q < 16; q++) {
        float4 v = *(const float4*)(row + q * 4);
        hr[q*4] = v.x; hr[q*4+1] = v.y; hr[q*4+2] = v.z; hr[q*4+3] = v.w;
    }
    float o0 = db2[0], o1 = db2[1];
    for (int jc = 0; jc < 4; jc++) {
        float acc[16];
        #pragma unroll
        for (int jj = 0; jj < 16; jj++) acc[jj] = db1[jc * 16 + jj];
        #pragma unroll
        for (int k = 0; k < DEMB; k++) {
            float hk = hr[k];
            #pragma unroll
            for (int jj = 0; jj < 16; jj++)
                acc[jj] = fmaf(hk, dw1[k * DEMB + jc * 16 + jj], acc[jj]);
        }
        #pragma unroll
        for (int jj = 0; jj < 16; jj++) {
            float dv = fmaxf(acc[jj], 0.0f);
            int j = jc * 16 + jj;
            o0 = fmaf(dv, dw2[j * 2 + 0], o0);
            o1 = fmaf(dv, dw2[j * 2 + 1], o1);
        }
    }
    float m = fmaxf(o0, o1);
    float e0 = expf(o0 - m), e1 = expf(o1 - m);
    float inv = 1.0f / (e0 + e1);
    out[2 * n]     = e0 * inv + 2.0f * x[2 * n];  // wc = [2, 0]
    out[2 * n + 1] = e1 * inv;
}

// ---------------- launch ----------------

extern "C" void kernel_launch(void* const* d_in, const int* in_sizes, int n_in,
                              void* d_out, int out_size, void* d_ws, size_t ws_size,
                              hipStream_t stream) {
    const float* x      = (const float*)d_in[0];
    const int*   ei     = (const int*)d_in[1];
    const float* ew     = (const float*)d_in[2];
    const float* enc_w1 = (const float*)d_in[3];
    const float* enc_b1 = (const float*)d_in[4];
    const float* enc_w2 = (const float*)d_in[5];
    const float* enc_b2 = (const float*)d_in[6];
    const float* gcn_w  = (const float*)d_in[7];
    const float* gcn_b  = (const float*)d_in[8];
    const float* dec_w1 = (const float*)d_in[9];
    const float* dec_b1 = (const float*)d_in[10];
    const float* dec_w2 = (const float*)d_in[11];
    const float* dec_b2 = (const float*)d_in[12];
    float* out = (float*)d_out;

    const int N = in_sizes[0] / 2;
    const int E = in_sizes[2];
    const int L = in_sizes[7] / (DEMB * DEMB);

    // workspace layout (256B aligned)
    char* ws = (char*)d_ws;
    size_t o = 0;
    auto alignup = [](size_t v) { return (v + 255) & ~(size_t)255; };
    float* h      = (float*)(ws + o); o = alignup(o + (size_t)N * DEMB * 4);
    float* hw     = (float*)(ws + o); o = alignup(o + (size_t)N * DEMB * 4);
    float* dis    = (float*)(ws + o); o = alignup(o + (size_t)N * 4);       // deg, then rsqrt in place
    int*   cnt    = (int*)(ws + o);   o = alignup(o + (size_t)N * 4);
    int*   rowptr = (int*)(ws + o);   o = alignup(o + (size_t)(N + 1) * 4);
    int*   fill   = (int*)(ws + o);   o = alignup(o + (size_t)N * 4);
    int*   csr_src= (int*)(ws + o);   o = alignup(o + (size_t)E * 4);
    float* csr_w  = (float*)(ws + o); o = alignup(o + (size_t)E * 4);

    const int TB = 256;
    dim3 blk(TB);
    dim3 gN((N + TB - 1) / TB);
    dim3 gE((E + TB - 1) / TB);
    dim3 gWave((N * 64 + TB - 1) / TB);   // wave-per-node kernels

    init_kernel<<<gN, blk, 0, stream>>>(dis, cnt, fill, N);
    deg_hist_kernel<<<gE, blk, 0, stream>>>(ei, ew, dis, cnt, E);
    dis_kernel<<<gN, blk, 0, stream>>>(dis, N);
    scan_kernel<<<1, 1024, 0, stream>>>(cnt, rowptr, N);
    csr_fill_kernel<<<gE, blk, 0, stream>>>(ei, ew, dis, rowptr, fill, csr_src, csr_w, E);

    encoder_kernel<<<gN, blk, 0, stream>>>(x, enc_w1, enc_b1, enc_w2, enc_b2, h, N);

    for (int l = 0; l < L; l++) {
        transform_kernel<<<gN, blk, 0, stream>>>(h, gcn_w + (size_t)l * DEMB * DEMB, hw, N);
        aggregate_kernel<<<gWave, blk, 0, stream>>>(hw, rowptr, csr_src, csr_w, dis,
                                                    gcn_b + (size_t)l * DEMB, h, N);
    }

    decoder_kernel<<<gN, blk, 0, stream>>>(h, x, dec_w1, dec_b1, dec_w2, dec_b2, out, N);
}

// Round 2
// 1061.943 us; speedup vs baseline: 1.8587x; 1.8587x over previous
//
#include <hip/hip_runtime.h>
#include <hip/hip_bf16.h>
#include <math.h>

#define DEMB 64
#define M_NODES 4

// ---------------- helpers ----------------

__device__ __forceinline__ float bf2f(unsigned short u) {
    union { unsigned int i; float f; } c; c.i = ((unsigned int)u) << 16; return c.f;
}
__device__ __forceinline__ unsigned short f2bf(float f) {
    union { float f; unsigned int i; } c; c.f = f;
    unsigned int r = c.i + 0x7FFFu + ((c.i >> 16) & 1u);   // RNE
    return (unsigned short)(r >> 16);
}
__device__ __forceinline__ float rdlane(float v, int k) {
    return __int_as_float(__builtin_amdgcn_readlane(__float_as_int(v), k));
}

// ---------------- graph preprocessing ----------------

__global__ void init_kernel(float* __restrict__ deg, int* __restrict__ cnt,
                            int* __restrict__ fill, int N) {
    int i = blockIdx.x * blockDim.x + threadIdx.x;
    if (i >= N) return;
    deg[i] = 1.0f;   // self-loop weight
    cnt[i] = 0;
    fill[i] = 0;
}

__global__ void deg_hist_kernel(const int* __restrict__ ei, const float* __restrict__ ew,
                                float* __restrict__ deg, int* __restrict__ cnt, int E) {
    int e = blockIdx.x * blockDim.x + threadIdx.x;
    if (e >= E) return;
    int c = ei[E + e];           // col (target)
    atomicAdd(&deg[c], ew[e]);
    atomicAdd(&cnt[c], 1);
}

__global__ void dis_kernel(float* __restrict__ deg, int N) {
    int i = blockIdx.x * blockDim.x + threadIdx.x;
    if (i >= N) return;
    deg[i] = rsqrtf(deg[i]);     // deg >= 1 always (self loop)
}

// single-block exclusive scan of cnt -> rowptr (rowptr[N] = E)
__global__ void scan_kernel(const int* __restrict__ cnt, int* __restrict__ rowptr, int N) {
    __shared__ int part[1024];
    int t = threadIdx.x;
    int chunk = (N + 1023) >> 10;
    int lo = t * chunk;
    int hi = lo + chunk; if (hi > N) hi = N;
    int s = 0;
    for (int i = lo; i < hi; i++) s += cnt[i];
    part[t] = s;
    __syncthreads();
    for (int off = 1; off < 1024; off <<= 1) {
        int v = (t >= off) ? part[t - off] : 0;
        __syncthreads();
        part[t] += v;
        __syncthreads();
    }
    int run = part[t] - s;       // exclusive prefix
    for (int i = lo; i < hi; i++) { rowptr[i] = run; run += cnt[i]; }
    if (lo < N && hi == N) rowptr[N] = run;
}

__global__ void csr_fill_kernel(const int* __restrict__ ei, const float* __restrict__ ew,
                                const float* __restrict__ dis, const int* __restrict__ rowptr,
                                int* __restrict__ fill, int2* __restrict__ csr, int E) {
    int e = blockIdx.x * blockDim.x + threadIdx.x;
    if (e >= E) return;
    int r = ei[e];
    int c = ei[E + e];
    int pos = rowptr[c] + atomicAdd(&fill[c], 1);
    int2 ent;
    ent.x = r;
    ent.y = __float_as_int(dis[r] * ew[e] * dis[c]);
    csr[pos] = ent;
}

// ---------------- encoder: wave handles M_NODES nodes, lane = feature ----------------

__global__ __launch_bounds__(256, 4) void encoder_kernel(
    const float* __restrict__ x,
    const float* __restrict__ w1, const float* __restrict__ b1,
    const float* __restrict__ w2, const float* __restrict__ b2,
    unsigned short* __restrict__ hout, int N) {
    int lane = threadIdx.x & 63;
    int wid = __builtin_amdgcn_readfirstlane((blockIdx.x * blockDim.x + threadIdx.x) >> 6);
    int n0 = wid * M_NODES;
    if (n0 >= N) return;

    float w2col[DEMB];
    #pragma unroll
    for (int k = 0; k < DEMB; k++) w2col[k] = w2[k * DEMB + lane];
    float w1a = w1[lane], w1b = w1[DEMB + lane];
    float b1v = b1[lane], b2v = b2[lane];

    // cooperative x load: lanes 0..2*M_NODES-1 grab x pairs for the wave's nodes
    float xv = 0.0f;
    if (lane < 2 * M_NODES && n0 * 2 + lane < 2 * N) xv = x[n0 * 2 + lane];

    #pragma unroll
    for (int m = 0; m < M_NODES; m++) {
        int node = n0 + m;
        if (node >= N) continue;
        float x0 = rdlane(xv, 2 * m);
        float x1 = rdlane(xv, 2 * m + 1);
        float t = fmaxf(0.0f, fmaf(x0, w1a, fmaf(x1, w1b, b1v)));   // t[lane]
        float y = b2v;
        #pragma unroll
        for (int k = 0; k < DEMB; k++)
            y = fmaf(rdlane(t, k), w2col[k], y);
        hout[(size_t)node * DEMB + lane] = f2bf(y);   // no ReLU on encoder output
    }
}

// ------- fused layer: aggregate (A*h) then transform (*W) + bias + ReLU -------
// h_next = relu( (A h) W + b )   [valid by associativity: A(hW) = (Ah)W]

__global__ __launch_bounds__(256, 4) void layer_kernel(
    const unsigned short* __restrict__ hin, const int2* __restrict__ csr,
    const int* __restrict__ rowptr, const float* __restrict__ dis,
    const float* __restrict__ W, const float* __restrict__ bias,
    unsigned short* __restrict__ hout, int N) {
    int lane = threadIdx.x & 63;
    int wid = __builtin_amdgcn_readfirstlane((blockIdx.x * blockDim.x + threadIdx.x) >> 6);
    int n0 = wid * M_NODES;
    if (n0 >= N) return;

    float Wcol[DEMB];
    #pragma unroll
    for (int k = 0; k < DEMB; k++) Wcol[k] = W[k * DEMB + lane];
    float bv = bias[lane];

    float acc[M_NODES];
    #pragma unroll
    for (int m = 0; m < M_NODES; m++) {
        int node = n0 + m;
        if (node >= N) { acc[m] = 0.0f; continue; }
        float d = dis[node];
        acc[m] = d * d * bf2f(hin[(size_t)node * DEMB + lane]);   // self loop
        int s = rowptr[node], e = rowptr[node + 1];
        for (int i = s; i < e; i++) {
            int2 ent = csr[i];
            acc[m] = fmaf(__int_as_float(ent.y),
                          bf2f(hin[(size_t)ent.x * DEMB + lane]), acc[m]);
        }
    }

    #pragma unroll
    for (int m = 0; m < M_NODES; m++) {
        int node = n0 + m;
        if (node >= N) continue;
        float y = bv;
        #pragma unroll
        for (int k = 0; k < DEMB; k++)
            y = fmaf(rdlane(acc[m], k), Wcol[k], y);
        hout[(size_t)node * DEMB + lane] = f2bf(fmaxf(y, 0.0f));
    }
}

// ---------------- decoder + softmax + residual ----------------

__global__ __launch_bounds__(256, 4) void decoder_kernel(
    const unsigned short* __restrict__ h, const float* __restrict__ x,
    const float* __restrict__ dw1, const float* __restrict__ db1,
    const float* __restrict__ dw2, const float* __restrict__ db2,
    float* __restrict__ out, int N) {
    int lane = threadIdx.x & 63;
    int wid = __builtin_amdgcn_readfirstlane((blockIdx.x * blockDim.x + threadIdx.x) >> 6);
    int n0 = wid * M_NODES;
    if (n0 >= N) return;

    float w1col[DEMB];
    #pragma unroll
    for (int k = 0; k < DEMB; k++) w1col[k] = dw1[k * DEMB + lane];
    float db1v = db1[lane];
    float w20 = dw2[lane * 2], w21 = dw2[lane * 2 + 1];
    float db20 = db2[0], db21 = db2[1];

    // cooperative x load for residual
    float xv = 0.0f;
    if (lane < 2 * M_NODES && n0 * 2 + lane < 2 * N) xv = x[n0 * 2 + lane];

    float myout = 0.0f;
    #pragma unroll
    for (int m = 0; m < M_NODES; m++) {
        int node = n0 + m;
        if (node >= N) continue;
        float hv = bf2f(h[(size_t)node * DEMB + lane]);
        float y = db1v;
        #pragma unroll
        for (int k = 0; k < DEMB; k++)
            y = fmaf(rdlane(hv, k), w1col[k], y);
        float d1 = fmaxf(y, 0.0f);
        float p0 = d1 * w20, p1 = d1 * w21;
        #pragma unroll
        for (int off = 32; off > 0; off >>= 1) {
            p0 += __shfl_xor(p0, off);
            p1 += __shfl_xor(p1, off);
        }
        float o0 = p0 + db20, o1 = p1 + db21;
        float mm = fmaxf(o0, o1);
        float e0 = __expf(o0 - mm), e1 = __expf(o1 - mm);
        float inv = 1.0f / (e0 + e1);
        float r0 = e0 * inv + 2.0f * rdlane(xv, 2 * m);   // wc = [2, 0]
        float r1 = e1 * inv;
        if (lane == 2 * m) myout = r0;
        if (lane == 2 * m + 1) myout = r1;
    }
    // coalesced write: lanes 0..2*M_NODES-1 hold out[n0*2 + lane]
    if (lane < 2 * M_NODES && n0 * 2 + lane < 2 * N)
        out[n0 * 2 + lane] = myout;
}

// ---------------- launch ----------------

extern "C" void kernel_launch(void* const* d_in, const int* in_sizes, int n_in,
                              void* d_out, int out_size, void* d_ws, size_t ws_size,
                              hipStream_t stream) {
    const float* x      = (const float*)d_in[0];
    const int*   ei     = (const int*)d_in[1];
    const float* ew     = (const float*)d_in[2];
    const float* enc_w1 = (const float*)d_in[3];
    const float* enc_b1 = (const float*)d_in[4];
    const float* enc_w2 = (const float*)d_in[5];
    const float* enc_b2 = (const float*)d_in[6];
    const float* gcn_w  = (const float*)d_in[7];
    const float* gcn_b  = (const float*)d_in[8];
    const float* dec_w1 = (const float*)d_in[9];
    const float* dec_b1 = (const float*)d_in[10];
    const float* dec_w2 = (const float*)d_in[11];
    const float* dec_b2 = (const float*)d_in[12];
    float* out = (float*)d_out;

    const int N = in_sizes[0] / 2;
    const int E = in_sizes[2];
    const int L = in_sizes[7] / (DEMB * DEMB);

    // workspace layout (256B aligned)
    char* ws = (char*)d_ws;
    size_t o = 0;
    auto alignup = [](size_t v) { return (v + 255) & ~(size_t)255; };
    unsigned short* hA = (unsigned short*)(ws + o); o = alignup(o + (size_t)N * DEMB * 2);
    unsigned short* hB = (unsigned short*)(ws + o); o = alignup(o + (size_t)N * DEMB * 2);
    float* dis    = (float*)(ws + o); o = alignup(o + (size_t)N * 4);   // deg, then rsqrt in place
    int*   cnt    = (int*)(ws + o);   o = alignup(o + (size_t)N * 4);
    int*   rowptr = (int*)(ws + o);   o = alignup(o + (size_t)(N + 1) * 4);
    int*   fill   = (int*)(ws + o);   o = alignup(o + (size_t)N * 4);
    int2*  csr    = (int2*)(ws + o);  o = alignup(o + (size_t)E * 8);

    const int TB = 256;
    dim3 blk(TB);
    dim3 gN((N + TB - 1) / TB);
    dim3 gE((E + TB - 1) / TB);
    int waves = (N + M_NODES - 1) / M_NODES;
    dim3 gWaveM((waves + 3) / 4);   // 4 waves per 256-thread block

    init_kernel<<<gN, blk, 0, stream>>>(dis, cnt, fill, N);
    deg_hist_kernel<<<gE, blk, 0, stream>>>(ei, ew, dis, cnt, E);
    dis_kernel<<<gN, blk, 0, stream>>>(dis, N);
    scan_kernel<<<1, 1024, 0, stream>>>(cnt, rowptr, N);
    csr_fill_kernel<<<gE, blk, 0, stream>>>(ei, ew, dis, rowptr, fill, csr, E);

    encoder_kernel<<<gWaveM, blk, 0, stream>>>(x, enc_w1, enc_b1, enc_w2, enc_b2, hA, N);

    unsigned short* hin = hA;
    unsigned short* hout = hB;
    for (int l = 0; l < L; l++) {
        layer_kernel<<<gWaveM, blk, 0, stream>>>(hin, csr, rowptr, dis,
                                                 gcn_w + (size_t)l * DEMB * DEMB,
                                                 gcn_b + (size_t)l * DEMB, hout, N);
        unsigned short* t = hin; hin = hout; hout = t;
    }

    decoder_kernel<<<gWaveM, blk, 0, stream>>>(hin, x, dec_w1, dec_b1, dec_w2, dec_b2, out, N);
}

// Round 3
// 652.829 us; speedup vs baseline: 3.0236x; 1.6267x over previous
//
#include <hip/hip_runtime.h>
#include <hip/hip_bf16.h>
#include <math.h>

#define DEMB 64
#define M_NODES 4

// ---------------- helpers ----------------

__device__ __forceinline__ float bf2f(unsigned short u) {
    union { unsigned int i; float f; } c; c.i = ((unsigned int)u) << 16; return c.f;
}
__device__ __forceinline__ unsigned short f2bf(float f) {
    union { float f; unsigned int i; } c; c.f = f;
    unsigned int r = c.i + 0x7FFFu + ((c.i >> 16) & 1u);   // RNE
    return (unsigned short)(r >> 16);
}
__device__ __forceinline__ float rdlane(float v, int k) {
    return __int_as_float(__builtin_amdgcn_readlane(__float_as_int(v), k));
}

// ---------------- graph preprocessing ----------------

__global__ void init_kernel(unsigned long long* __restrict__ packed,
                            int* __restrict__ fill, int N) {
    int i = blockIdx.x * blockDim.x + threadIdx.x;
    if (i >= N) return;
    packed[i] = 0ULL;
    fill[i] = 0;
}

// one u64 atomic per edge: [cnt:16][deg fixpoint 2^32:48]
__global__ void deg_hist_kernel(const int* __restrict__ ei, const float* __restrict__ ew,
                                unsigned long long* __restrict__ packed, int E) {
    int e = blockIdx.x * blockDim.x + threadIdx.x;
    if (e >= E) return;
    int c = ei[E + e];           // col (target)
    unsigned long long add = (1ULL << 48) |
        (unsigned long long)(ew[e] * 4294967296.0f);
    atomicAdd(&packed[c], add);
}

__global__ void dis_kernel(const unsigned long long* __restrict__ packed,
                           float* __restrict__ dis, int* __restrict__ cnt, int N) {
    int i = blockIdx.x * blockDim.x + threadIdx.x;
    if (i >= N) return;
    unsigned long long p = packed[i];
    cnt[i] = (int)(p >> 48);
    float deg = 1.0f + (float)(p & 0xFFFFFFFFFFFFULL) * (1.0f / 4294967296.0f);
    dis[i] = rsqrtf(deg);        // deg >= 1 (self loop)
}

// -------- 3-phase multi-block scan: cnt[N] -> rowptr[N+1] (exclusive) --------
// phase 1: per-block (1024 elems) sums
__global__ __launch_bounds__(256) void scan_sums_kernel(const int* __restrict__ cnt,
                                                        int* __restrict__ part, int N) {
    int b = blockIdx.x, t = threadIdx.x, lane = t & 63, w = t >> 6;
    int idx = b * 1024 + t * 4;
    int s = 0;
    if (idx + 3 < N) {
        int4 v = *(const int4*)(cnt + idx);
        s = v.x + v.y + v.z + v.w;
    } else {
        for (int j = 0; j < 4; j++) if (idx + j < N) s += cnt[idx + j];
    }
    #pragma unroll
    for (int off = 32; off > 0; off >>= 1) s += __shfl_down(s, off);
    __shared__ int wt[4];
    if (lane == 0) wt[w] = s;
    __syncthreads();
    if (t == 0) part[b] = wt[0] + wt[1] + wt[2] + wt[3];
}

// phase 2: single block scans the partials (NB <= 1024), writes rowptr[N]=total
__global__ void scan_offsets_kernel(int* __restrict__ part, int* __restrict__ rowptr,
                                    int NB, int N) {
    __shared__ int sh[1024];
    int t = threadIdx.x;
    int mine = (t < NB) ? part[t] : 0;
    sh[t] = mine;
    __syncthreads();
    for (int off = 1; off < 1024; off <<= 1) {
        int v = (t >= off) ? sh[t - off] : 0;
        __syncthreads();
        sh[t] += v;
        __syncthreads();
    }
    if (t < NB) part[t] = sh[t] - mine;   // exclusive
    if (t == 1023) rowptr[N] = sh[1023];  // total = E
}

// phase 3: block-local scan + offset -> rowptr
__global__ __launch_bounds__(256) void scan_apply_kernel(const int* __restrict__ cnt,
                                                         const int* __restrict__ part,
                                                         int* __restrict__ rowptr, int N) {
    int b = blockIdx.x, t = threadIdx.x, lane = t & 63, w = t >> 6;
    int idx = b * 1024 + t * 4;
    int v0 = 0, v1 = 0, v2 = 0, v3 = 0;
    if (idx + 3 < N) {
        int4 v = *(const int4*)(cnt + idx);
        v0 = v.x; v1 = v.y; v2 = v.z; v3 = v.w;
    } else {
        if (idx     < N) v0 = cnt[idx];
        if (idx + 1 < N) v1 = cnt[idx + 1];
        if (idx + 2 < N) v2 = cnt[idx + 2];
        if (idx + 3 < N) v3 = cnt[idx + 3];
    }
    int tsum = v0 + v1 + v2 + v3;
    int sc = tsum;
    #pragma unroll
    for (int off = 1; off < 64; off <<= 1) {
        int u = __shfl_up(sc, off);
        if (lane >= off) sc += u;
    }
    __shared__ int wt[4];
    if (lane == 63) wt[w] = sc;
    __syncthreads();
    int woff = 0;
    for (int i = 0; i < w; i++) woff += wt[i];
    int ex = part[b] + woff + sc - tsum;
    if (idx + 3 < N) {
        int4 o;
        o.x = ex; o.y = ex + v0; o.z = ex + v0 + v1; o.w = ex + v0 + v1 + v2;
        *(int4*)(rowptr + idx) = o;
    } else {
        if (idx     < N) rowptr[idx]     = ex;
        if (idx + 1 < N) rowptr[idx + 1] = ex + v0;
        if (idx + 2 < N) rowptr[idx + 2] = ex + v0 + v1;
        if (idx + 3 < N) rowptr[idx + 3] = ex + v0 + v1 + v2;
    }
}

// csr entry: (src, ew) — dis factors applied via scaled node state
__global__ void csr_fill_kernel(const int* __restrict__ ei, const float* __restrict__ ew,
                                const int* __restrict__ rowptr,
                                int* __restrict__ fill, int2* __restrict__ csr, int E) {
    int e = blockIdx.x * blockDim.x + threadIdx.x;
    if (e >= E) return;
    int r = ei[e];
    int c = ei[E + e];
    int pos = rowptr[c] + atomicAdd(&fill[c], 1);
    int2 ent;
    ent.x = r;
    ent.y = __float_as_int(ew[e]);
    csr[pos] = ent;
}

// ---------------- encoder: stores s = dis * h_enc ----------------

__global__ __launch_bounds__(256, 4) void encoder_kernel(
    const float* __restrict__ x, const float* __restrict__ dis,
    const float* __restrict__ w1, const float* __restrict__ b1,
    const float* __restrict__ w2, const float* __restrict__ b2,
    unsigned short* __restrict__ hout, int N) {
    int lane = threadIdx.x & 63;
    int wid = __builtin_amdgcn_readfirstlane((blockIdx.x * blockDim.x + threadIdx.x) >> 6);
    int n0 = wid * M_NODES;
    if (n0 >= N) return;

    float w2col[DEMB];
    #pragma unroll
    for (int k = 0; k < DEMB; k++) w2col[k] = w2[k * DEMB + lane];
    float w1a = w1[lane], w1b = w1[DEMB + lane];
    float b1v = b1[lane], b2v = b2[lane];

    float xv = 0.0f;
    if (lane < 2 * M_NODES && n0 * 2 + lane < 2 * N) xv = x[n0 * 2 + lane];

    #pragma unroll
    for (int m = 0; m < M_NODES; m++) {
        int node = n0 + m;
        if (node >= N) continue;
        float x0 = rdlane(xv, 2 * m);
        float x1 = rdlane(xv, 2 * m + 1);
        float t = fmaxf(0.0f, fmaf(x0, w1a, fmaf(x1, w1b, b1v)));
        float y = b2v;
        #pragma unroll
        for (int k = 0; k < DEMB; k++)
            y = fmaf(rdlane(t, k), w2col[k], y);
        hout[(size_t)node * DEMB + lane] = f2bf(y * dis[node]);  // scaled state
    }
}

// ------- fused layer on scaled state: sin = dis*h; agg = dis_c*(Σ ew*sin[src] + sin[c]) -------
// h_next = relu(agg·W + b); store (scaleOut ? dis_c : 1) * h_next

__global__ __launch_bounds__(256, 4) void layer_kernel(
    const unsigned short* __restrict__ hin, const int2* __restrict__ csr,
    const int* __restrict__ rowptr, const float* __restrict__ dis,
    const float* __restrict__ W, const float* __restrict__ bias,
    unsigned short* __restrict__ hout, int N, int scaleOut) {
    int lane = threadIdx.x & 63;
    int wid = __builtin_amdgcn_readfirstlane((blockIdx.x * blockDim.x + threadIdx.x) >> 6);
    int n0 = wid * M_NODES;
    if (n0 >= N) return;

    float Wcol[DEMB];
    #pragma unroll
    for (int k = 0; k < DEMB; k++) Wcol[k] = W[k * DEMB + lane];
    float bv = bias[lane];

    float acc[M_NODES];
    #pragma unroll
    for (int m = 0; m < M_NODES; m++) {
        int node = n0 + m;
        if (node >= N) { acc[m] = 0.0f; continue; }
        float a = bf2f(hin[(size_t)node * DEMB + lane]);   // self loop term (s_c)
        int s = rowptr[node], e = rowptr[node + 1];
        int i = s;
        for (; i + 8 <= e; i += 8) {
            int2 mm[8];
            #pragma unroll
            for (int j = 0; j < 8; j++) mm[j] = csr[i + j];
            float hv[8];
            #pragma unroll
            for (int j = 0; j < 8; j++)
                hv[j] = bf2f(hin[(size_t)mm[j].x * DEMB + lane]);
            #pragma unroll
            for (int j = 0; j < 8; j++)
                a = fmaf(__int_as_float(mm[j].y), hv[j], a);
        }
        for (; i < e; i++) {
            int2 ent = csr[i];
            a = fmaf(__int_as_float(ent.y), bf2f(hin[(size_t)ent.x * DEMB + lane]), a);
        }
        acc[m] = a;
    }

    #pragma unroll
    for (int m = 0; m < M_NODES; m++) {
        int node = n0 + m;
        if (node >= N) continue;
        float d = dis[node];
        float dot = 0.0f;
        #pragma unroll
        for (int k = 0; k < DEMB; k++)
            dot = fmaf(rdlane(acc[m], k), Wcol[k], dot);
        float y = fmaxf(fmaf(d, dot, bv), 0.0f);
        float os = scaleOut ? d : 1.0f;
        hout[(size_t)node * DEMB + lane] = f2bf(y * os);
    }
}

// ---------------- decoder + softmax + residual ----------------

__global__ __launch_bounds__(256, 4) void decoder_kernel(
    const unsigned short* __restrict__ h, const float* __restrict__ x,
    const float* __restrict__ dw1, const float* __restrict__ db1,
    const float* __restrict__ dw2, const float* __restrict__ db2,
    float* __restrict__ out, int N) {
    int lane = threadIdx.x & 63;
    int wid = __builtin_amdgcn_readfirstlane((blockIdx.x * blockDim.x + threadIdx.x) >> 6);
    int n0 = wid * M_NODES;
    if (n0 >= N) return;

    float w1col[DEMB];
    #pragma unroll
    for (int k = 0; k < DEMB; k++) w1col[k] = dw1[k * DEMB + lane];
    float db1v = db1[lane];
    float w20 = dw2[lane * 2], w21 = dw2[lane * 2 + 1];
    float db20 = db2[0], db21 = db2[1];

    float xv = 0.0f;
    if (lane < 2 * M_NODES && n0 * 2 + lane < 2 * N) xv = x[n0 * 2 + lane];

    float myout = 0.0f;
    #pragma unroll
    for (int m = 0; m < M_NODES; m++) {
        int node = n0 + m;
        if (node >= N) continue;
        float hv = bf2f(h[(size_t)node * DEMB + lane]);
        float y = db1v;
        #pragma unroll
        for (int k = 0; k < DEMB; k++)
            y = fmaf(rdlane(hv, k), w1col[k], y);
        float d1 = fmaxf(y, 0.0f);
        float p0 = d1 * w20, p1 = d1 * w21;
        #pragma unroll
        for (int off = 32; off > 0; off >>= 1) {
            p0 += __shfl_xor(p0, off);
            p1 += __shfl_xor(p1, off);
        }
        float o0 = p0 + db20, o1 = p1 + db21;
        float mm = fmaxf(o0, o1);
        float e0 = __expf(o0 - mm), e1 = __expf(o1 - mm);
        float inv = 1.0f / (e0 + e1);
        float r0 = e0 * inv + 2.0f * rdlane(xv, 2 * m);   // wc = [2, 0]
        float r1 = e1 * inv;
        if (lane == 2 * m) myout = r0;
        if (lane == 2 * m + 1) myout = r1;
    }
    if (lane < 2 * M_NODES && n0 * 2 + lane < 2 * N)
        out[n0 * 2 + lane] = myout;
}

// ---------------- launch ----------------

extern "C" void kernel_launch(void* const* d_in, const int* in_sizes, int n_in,
                              void* d_out, int out_size, void* d_ws, size_t ws_size,
                              hipStream_t stream) {
    const float* x      = (const float*)d_in[0];
    const int*   ei     = (const int*)d_in[1];
    const float* ew     = (const float*)d_in[2];
    const float* enc_w1 = (const float*)d_in[3];
    const float* enc_b1 = (const float*)d_in[4];
    const float* enc_w2 = (const float*)d_in[5];
    const float* enc_b2 = (const float*)d_in[6];
    const float* gcn_w  = (const float*)d_in[7];
    const float* gcn_b  = (const float*)d_in[8];
    const float* dec_w1 = (const float*)d_in[9];
    const float* dec_b1 = (const float*)d_in[10];
    const float* dec_w2 = (const float*)d_in[11];
    const float* dec_b2 = (const float*)d_in[12];
    float* out = (float*)d_out;

    const int N = in_sizes[0] / 2;
    const int E = in_sizes[2];
    const int L = in_sizes[7] / (DEMB * DEMB);

    // workspace layout (256B aligned)
    char* ws = (char*)d_ws;
    size_t o = 0;
    auto alignup = [](size_t v) { return (v + 255) & ~(size_t)255; };
    unsigned short* hA = (unsigned short*)(ws + o); o = alignup(o + (size_t)N * DEMB * 2);
    unsigned short* hB = (unsigned short*)(ws + o); o = alignup(o + (size_t)N * DEMB * 2);
    unsigned long long* packed = (unsigned long long*)(ws + o); o = alignup(o + (size_t)N * 8);
    float* dis    = (float*)(ws + o); o = alignup(o + (size_t)N * 4);
    int*   cnt    = (int*)(ws + o);   o = alignup(o + (size_t)N * 4);
    int*   rowptr = (int*)(ws + o);   o = alignup(o + (size_t)(N + 1) * 4);
    int*   fill   = (int*)(ws + o);   o = alignup(o + (size_t)N * 4);
    int*   part   = (int*)(ws + o);   o = alignup(o + (size_t)1024 * 4);
    int2*  csr    = (int2*)(ws + o);  o = alignup(o + (size_t)E * 8);

    const int TB = 256;
    dim3 blk(TB);
    dim3 gN((N + TB - 1) / TB);
    dim3 gE((E + TB - 1) / TB);
    int NB = (N + 1023) >> 10;          // scan blocks (1024 elems each)
    int waves = (N + M_NODES - 1) / M_NODES;
    dim3 gWaveM((waves + 3) / 4);       // 4 waves per 256-thread block

    init_kernel<<<gN, blk, 0, stream>>>(packed, fill, N);
    deg_hist_kernel<<<gE, blk, 0, stream>>>(ei, ew, packed, E);
    dis_kernel<<<gN, blk, 0, stream>>>(packed, dis, cnt, N);
    scan_sums_kernel<<<NB, blk, 0, stream>>>(cnt, part, N);
    scan_offsets_kernel<<<1, 1024, 0, stream>>>(part, rowptr, NB, N);
    scan_apply_kernel<<<NB, blk, 0, stream>>>(cnt, part, rowptr, N);
    csr_fill_kernel<<<gE, blk, 0, stream>>>(ei, ew, rowptr, fill, csr, E);

    encoder_kernel<<<gWaveM, blk, 0, stream>>>(x, dis, enc_w1, enc_b1, enc_w2, enc_b2, hA, N);

    unsigned short* hin = hA;
    unsigned short* hout = hB;
    for (int l = 0; l < L; l++) {
        layer_kernel<<<gWaveM, blk, 0, stream>>>(hin, csr, rowptr, dis,
                                                 gcn_w + (size_t)l * DEMB * DEMB,
                                                 gcn_b + (size_t)l * DEMB, hout, N,
                                                 (l < L - 1) ? 1 : 0);
        unsigned short* t = hin; hin = hout; hout = t;
    }

    decoder_kernel<<<gWaveM, blk, 0, stream>>>(hin, x, dec_w1, dec_b1, dec_w2, dec_b2, out, N);
}